// Round 6
// baseline (265.360 us; speedup 1.0000x reference)
//
#include <hip/hip_runtime.h>

// Causal single-head attention, B=4 S=4096 Dm=256 Dqk=64, fp32 in/out.
// R6: attn at 2 blocks/CU. Task map nc(T)=T/6+1 -> 408 uniform blocks
// (chunks <=6 K-iters), launch_bounds(512,4); R3's proven loop order
// (S^T -> pack -> barrier -> prefetch -> PV; R5's rotation regressed).
// Split-T chunk 0 writes unnormalized fp32 directly to d_out (combine is the
// only later writer -> no atomics, no race); chunks >=1 write bf16 Op.
// Op = 280 slots x 64KB = 18.4MB; ws total 30.7MB (poison ~1.25us/MB).
// ws: qf 2MB + kf 2MB + vf 8MB + Op 18.4MB + Dp 196KB.

#define BATCH 4
#define SEQ   4096
#define DM    256
#define DQK   64

typedef __bf16 bf16x8 __attribute__((ext_vector_type(8)));
typedef float  f32x16 __attribute__((ext_vector_type(16)));

__device__ __forceinline__ unsigned int rnd16(unsigned int u) {
    return u + 0x7fffu + ((u >> 16) & 1u);          // RNE to bf16 in high half
}
__device__ __forceinline__ unsigned short f2bf(float f) {
    return (unsigned short)(rnd16(__builtin_bit_cast(unsigned int, f)) >> 16);
}
__device__ __forceinline__ unsigned int pk2bf(float lo, float hi) {
    unsigned int a = rnd16(__builtin_bit_cast(unsigned int, lo));
    unsigned int b = rnd16(__builtin_bit_cast(unsigned int, hi));
    return (a >> 16) | (b & 0xffff0000u);           // elem0 low, elem1 high
}
__device__ __forceinline__ bf16x8 u4bf(uint4 u) { return __builtin_bit_cast(bf16x8, u); }

// Repack a 32x32x16 MFMA accumulator D[m][n] (C-layout: col(n)=lane&31,
// row(m)=(r&3)+8(r>>2)+4(lane>>5)) into two 1KB fragment chunks where the
// fragment k-dim = m and lane-dim = n, then store. (Verified R2/R3.)
__device__ __forceinline__ void repack_store(const f32x16& acc, int q2, int l,
                                             uint4* __restrict__ out, size_t tile_ofs_u4) {
    unsigned int d0[4], d1[4], p0[4], p1[4];
#pragma unroll
    for (int h = 0; h < 4; ++h) {
        d0[h] = pk2bf(acc[4*h + 0], acc[4*h + 1]);
        d1[h] = pk2bf(acc[4*h + 2], acc[4*h + 3]);
        p0[h] = __shfl_xor((int)d0[h], 32);
        p1[h] = __shfl_xor((int)d1[h], 32);
    }
#pragma unroll
    for (int kc = 0; kc < 2; ++kc) {
        int h = 2*kc + q2;
        uint4 v = (q2 == 0) ? make_uint4(d0[h], d1[h], p0[h], p1[h])
                            : make_uint4(p0[h], p1[h], d0[h], d1[h]);
        out[tile_ofs_u4 + (size_t)kc * 64 + l] = v;
    }
}

// Partial-slot bases for task T (split iff T>=6, nc = T/6+1):
//   Op slots: chunks cc>=1 only -> nc-1 = T/6 slots; base = 3g(g-1)+(T-6g)g.
//   Dp slots: all chunks        -> base_d = base_o + (T-6).
__device__ __forceinline__ int obase(int T) {
    int g = T / 6;
    return 3*g*(g-1) + (T - 6*g)*g;
}

// ---------------------------------------------------------------------------
// Fused projection. grid (64 s-tiles, 4 batch, 4): z=0 Q, z=1 K, z=2 V(ec 0,1),
// z=3 V(ec 2,3). Coalesced fp32 staging -> bf16 LDS -> 32x32x16 MFMA ->
// frag-packed ws.
// ---------------------------------------------------------------------------
__global__ __launch_bounds__(256) void proj(const float* __restrict__ Xq,
                                            const float* __restrict__ Xk,
                                            const float* __restrict__ Xv,
                                            const float* __restrict__ Wq,
                                            const float* __restrict__ Wk,
                                            const float* __restrict__ Wv,
                                            uint4* __restrict__ qf,
                                            uint4* __restrict__ kf,
                                            uint4* __restrict__ vf) {
    __shared__ unsigned short Xs[64][264];
    __shared__ unsigned short Ws[64][264];

    const int z = blockIdx.z;
    const int bx = blockIdx.x, b = blockIdx.y;
    const float* X = (z == 0) ? Xq : (z == 1) ? Xk : Xv;
    const float* W = (z == 0) ? Wq : (z == 1) ? Wk : Wv;
    const int s0 = bx * 64;
    const int tid = threadIdx.x, w = tid >> 6, l = tid & 63, ln = l & 31, q2 = l >> 5;

#pragma unroll
    for (int i = 0; i < 16; ++i) {
        int f = i * 256 + tid;
        int r = f >> 6, c4 = f & 63;
        float4 xv = *(const float4*)&X[((size_t)b * SEQ + s0 + r) * DM + c4 * 4];
        ushort4 h; h.x = f2bf(xv.x); h.y = f2bf(xv.y); h.z = f2bf(xv.z); h.w = f2bf(xv.w);
        *(ushort4*)&Xs[r][c4 * 4] = h;
    }

    if (z < 2) {
        // ---- Q/K: D[m=e (64)][n=s (64)] ----
#pragma unroll
        for (int i = 0; i < 16; ++i) {
            int f = i * 256 + tid;
            int r = f >> 6, c4 = f & 63;
            float4 wv = *(const float4*)&W[(size_t)r * DM + c4 * 4];
            ushort4 h; h.x = f2bf(wv.x); h.y = f2bf(wv.y); h.z = f2bf(wv.z); h.w = f2bf(wv.w);
            *(ushort4*)&Ws[r][c4 * 4] = h;
        }
        __syncthreads();
        const int msub = w >> 1, nsub = w & 1;
        f32x16 a0 = {}, a1 = {};
#pragma unroll
        for (int c = 0; c < 16; c += 2) {
            bf16x8 af0 = u4bf(*(const uint4*)&Ws[msub*32 + ln][c*16 + q2*8]);
            bf16x8 bf0 = u4bf(*(const uint4*)&Xs[nsub*32 + ln][c*16 + q2*8]);
            a0 = __builtin_amdgcn_mfma_f32_32x32x16_bf16(af0, bf0, a0, 0, 0, 0);
            bf16x8 af1 = u4bf(*(const uint4*)&Ws[msub*32 + ln][(c+1)*16 + q2*8]);
            bf16x8 bf1 = u4bf(*(const uint4*)&Xs[nsub*32 + ln][(c+1)*16 + q2*8]);
            a1 = __builtin_amdgcn_mfma_f32_32x32x16_bf16(af1, bf1, a1, 0, 0, 0);
        }
        f32x16 acc = a0 + a1;
        size_t base = (((size_t)(b*128 + bx*2 + nsub)) * 4 + 2*msub) * 64;
        repack_store(acc, q2, l, (z == 0) ? qf : kf, base);
    } else {
        // ---- V: D[m=s (64)][n=e], e-chunks (z-2)*2 .. +1 ----
        const int msub = w & 1, nsub = w >> 1;
        for (int ecl = 0; ecl < 2; ++ecl) {
            const int ec = (z - 2) * 2 + ecl;
            __syncthreads();
#pragma unroll
            for (int i = 0; i < 16; ++i) {
                int f = i * 256 + tid;
                int r = f >> 6, c4 = f & 63;
                float4 wv = *(const float4*)&W[(size_t)(ec*64 + r) * DM + c4 * 4];
                ushort4 h; h.x = f2bf(wv.x); h.y = f2bf(wv.y); h.z = f2bf(wv.z); h.w = f2bf(wv.w);
                *(ushort4*)&Ws[r][c4 * 4] = h;
            }
            __syncthreads();
            f32x16 a0 = {}, a1 = {};
#pragma unroll
            for (int c = 0; c < 16; c += 2) {
                bf16x8 af0 = u4bf(*(const uint4*)&Xs[msub*32 + ln][c*16 + q2*8]);
                bf16x8 bf0 = u4bf(*(const uint4*)&Ws[nsub*32 + ln][c*16 + q2*8]);
                a0 = __builtin_amdgcn_mfma_f32_32x32x16_bf16(af0, bf0, a0, 0, 0, 0);
                bf16x8 af1 = u4bf(*(const uint4*)&Xs[msub*32 + ln][(c+1)*16 + q2*8]);
                bf16x8 bf1 = u4bf(*(const uint4*)&Ws[nsub*32 + ln][(c+1)*16 + q2*8]);
                a1 = __builtin_amdgcn_mfma_f32_32x32x16_bf16(af1, bf1, a1, 0, 0, 0);
            }
            f32x16 acc = a0 + a1;
            int et = ec*2 + nsub;
            size_t base = (((size_t)(b*8 + et)) * 256 + (size_t)bx*4 + msub*2) * 64;
            repack_store(acc, q2, l, vf, base);
        }
    }
}

// ---------------------------------------------------------------------------
// Attention. 408 blocks x 512 thr, 2 blocks/CU. Task = (b, T, chunk cc of
// nc = T/6+1). slot = bid&7: b = slot>>1, parity = slot&1 (XCD batch-pinning).
// Wave w: S^T tile (k-sub w&3, q-pair w>>2), PV e-tile w.
// Loop order = R3's proven: S^T -> exp/pack -> barrier -> prefetch -> PV.
// Epilogue: nc==1 -> normalized store; cc==0 -> unnormalized fp32 to out;
// cc>=1 -> bf16 Op. All split chunks write Dp.
// ---------------------------------------------------------------------------
__global__ __launch_bounds__(512, 4) void attn(const uint4* __restrict__ qf,
                                               const uint4* __restrict__ kf,
                                               const uint4* __restrict__ vf,
                                               float* __restrict__ out,
                                               unsigned short* __restrict__ Op,
                                               float* __restrict__ Dp) {
    __shared__ uint4 Pb[2][4][8][64];        // 64KB, double-buffered P
    __shared__ float denp[8][2][64];
    __shared__ float dfin[128];

    const int bid = blockIdx.x;
    const int slot = bid & 7, u = bid >> 3;
    const int b = slot >> 1;
    const int task = u * 2 + (slot & 1);     // [0,102)
    int T = 0, cc = 0, nc = 1, acc_t = 0;
    for (int t = 0; t < 32; ++t) {
        int n_t = t / 6 + 1;
        if (task < acc_t + n_t) { T = t; cc = task - acc_t; nc = n_t; break; }
        acc_t += n_t;
    }
    const int n = T + 1;
    const int j0 = cc * n / nc, j1 = (cc + 1) * n / nc;

    const int tid = threadIdx.x, w = tid >> 6, l = tid & 63, ln = l & 31, q2 = l >> 5;
    const int ks = w & 3, qp = w >> 2;
    const float cfac = 0.18033688011112042f; // log2(e)/sqrt(64)

    bf16x8 qv[2][4];
#pragma unroll
    for (int g = 0; g < 2; ++g)
#pragma unroll
        for (int c = 0; c < 4; ++c)
            qv[g][c] = u4bf(qf[(((size_t)b*128 + T*4 + qp*2 + g) * 4 + c) * 64 + l]);

    f32x16 oa[4] = {};
    float den[2] = {0.f, 0.f};

    uint4 kaf[4];
#pragma unroll
    for (int c = 0; c < 4; ++c)
        kaf[c] = kf[(((size_t)b*128 + j0*4 + ks) * 4 + c) * 64 + l];

    for (int jt = j0; jt < j1; ++jt) {
        const int buf = jt & 1;
        const bool diag = (jt == T);
        // ---- S^T ----
        f32x16 s0 = {}, s1 = {};
#pragma unroll
        for (int c = 0; c < 4; ++c) {
            bf16x8 ka = u4bf(kaf[c]);
            s0 = __builtin_amdgcn_mfma_f32_32x32x16_bf16(ka, qv[0][c], s0, 0, 0, 0);
            s1 = __builtin_amdgcn_mfma_f32_32x32x16_bf16(ka, qv[1][c], s1, 0, 0, 0);
        }
        // ---- exp + mask + den + pack P -> LDS ----
#pragma unroll
        for (int g = 0; g < 2; ++g) {
            const f32x16 s = g ? s1 : s0;
            const int qsub = qp*2 + g;
            float pv[16], pd = 0.f;
#pragma unroll
            for (int r = 0; r < 16; ++r) {
                float e = __builtin_exp2f(s[r] * cfac);
                if (diag) {
                    int klocal = 4*q2 + (r & 3) + 8*(r >> 2);
                    if (ks*32 + klocal > qsub*32 + ln) e = 0.f;
                }
                pv[r] = e; pd += e;
            }
            den[g] += pd;
#pragma unroll
            for (int quad = 0; quad < 4; ++quad) {
                unsigned int lo = pk2bf(pv[4*quad + 0], pv[4*quad + 1]);
                unsigned int hi = pk2bf(pv[4*quad + 2], pv[4*quad + 3]);
                int kcg = ks*2 + (quad >> 1);
                int h   = quad & 1;
                char* dst = (char*)&Pb[buf][qsub][kcg][h*32 + ln] + q2*8;
                *(uint2*)dst = make_uint2(lo, hi);
            }
        }
        __syncthreads();
        // prefetch next K-frags during PV
        if (jt + 1 < j1) {
#pragma unroll
            for (int c = 0; c < 4; ++c)
                kaf[c] = kf[(((size_t)b*128 + (jt+1)*4 + ks) * 4 + c) * 64 + l];
        }
        // ---- PV: O[q][e-tile w] += P * V ----
#pragma unroll
        for (int kc = 0; kc < 8; ++kc) {
            bf16x8 vb = u4bf(vf[(((size_t)b*8 + w) * 256 + (size_t)jt*8 + kc) * 64 + l]);
#pragma unroll
            for (int qs = 0; qs < 4; ++qs) {
                bf16x8 pa = u4bf(Pb[buf][qs][kc][l]);
                oa[qs] = __builtin_amdgcn_mfma_f32_32x32x16_bf16(pa, vb, oa[qs], 0, 0, 0);
            }
        }
    }

    // ---- den reduction across waves/halves ----
    denp[w][0][l] = den[0];
    denp[w][1][l] = den[1];
    __syncthreads();
    if (tid < 128) {
        int qsub = tid >> 5, qln = tid & 31;
        int g = qsub & 1, wp = qsub >> 1;
        float sden = 0.f;
#pragma unroll
        for (int k4 = 0; k4 < 4; ++k4)
#pragma unroll
            for (int hh = 0; hh < 2; ++hh)
                sden += denp[wp*4 + k4][g][hh*32 + qln];
        dfin[tid] = (nc == 1) ? 1.0f / sden : sden;
    }
    __syncthreads();

    if (nc == 1) {
#pragma unroll
        for (int qs = 0; qs < 4; ++qs)
#pragma unroll
            for (int r = 0; r < 16; ++r) {
                int qrow = qs*32 + (r & 3) + 8*(r >> 2) + 4*q2;
                out[((size_t)b*SEQ + T*128 + qrow) * DM + w*32 + ln] = oa[qs][r] * dfin[qrow];
            }
    } else if (cc == 0) {
        // chunk 0: unnormalized fp32 straight into out (combine divides later)
#pragma unroll
        for (int qs = 0; qs < 4; ++qs)
#pragma unroll
            for (int r = 0; r < 16; ++r) {
                int qrow = qs*32 + (r & 3) + 8*(r >> 2) + 4*q2;
                out[((size_t)b*SEQ + T*128 + qrow) * DM + w*32 + ln] = oa[qs][r];
            }
        if (tid < 128) Dp[((size_t)b*96 + obase(T) + (T - 6)) * 128 + tid] = dfin[tid];
    } else {
        size_t pidx = (size_t)b*70 + obase(T) + (cc - 1);
#pragma unroll
        for (int qs = 0; qs < 4; ++qs)
#pragma unroll
            for (int r = 0; r < 16; ++r) {
                int qrow = qs*32 + (r & 3) + 8*(r >> 2) + 4*q2;
                Op[(pidx*128 + qrow) * DM + w*32 + ln] = f2bf(oa[qs][r]);
            }
        if (tid < 128) Dp[((size_t)b*96 + obase(T) + (T - 6) + cc) * 128 + tid] = dfin[tid];
    }
}

// ---------------------------------------------------------------------------
// Combine partials for T in [6,32). grid (26, 4, 4 q-quarters) x 256 thr.
// out holds chunk-0's unnormalized fp32; add bf16 chunks >=1, divide by den.
// ---------------------------------------------------------------------------
__global__ __launch_bounds__(256) void combine(const unsigned short* __restrict__ Op,
                                               const float* __restrict__ Dp,
                                               float* __restrict__ out) {
    const int T = 6 + blockIdx.x, b = blockIdx.y, qq = blockIdx.z;
    const int nc = T / 6 + 1;
    const int t = threadIdx.x;
    const int ob = obase(T);
    const size_t dbase = (size_t)b*96 + ob + (T - 6);
    const size_t pbase = (size_t)b*70 + ob;
#pragma unroll 4
    for (int r = 0; r < 32; ++r) {
        int q = qq*32 + r;
        size_t oofs = ((size_t)b*SEQ + T*128 + q) * DM + t;
        float sum = out[oofs];
        float dsum = 0.f;
        for (int c = 0; c < nc; ++c) dsum += Dp[(dbase + c)*128 + q];
        for (int c = 1; c < nc; ++c) {
            unsigned int uv = Op[((pbase + c - 1)*128 + q) * DM + t];
            sum += __builtin_bit_cast(float, uv << 16);
        }
        out[oofs] = sum / dsum;
    }
}

// ---------------------------------------------------------------------------
extern "C" void kernel_launch(void* const* d_in, const int* in_sizes, int n_in,
                              void* d_out, int out_size, void* d_ws, size_t ws_size,
                              hipStream_t stream) {
    const float* enc_q = (const float*)d_in[0];
    const float* enc_k = (const float*)d_in[1];
    const float* enc_v = (const float*)d_in[2];
    // d_in[3] = mask (deterministic causal triu) — not needed
    const float* Wq = (const float*)d_in[4];
    const float* Wk = (const float*)d_in[5];
    const float* Wv = (const float*)d_in[6];
    float* out = (float*)d_out;

    uint4* qf = (uint4*)d_ws;                              // 2MB
    uint4* kf = qf + 131072;                               // 2MB
    uint4* vf = kf + 131072;                               // 8MB
    unsigned short* Op = (unsigned short*)(vf + 524288);   // [4][70][128][256] bf16, 18.4MB
    float* Dp = (float*)(Op + (size_t)4*70*128*256);       // [4][96][128] f32, 196KB

    proj<<<dim3(64, 4, 4), 256, 0, stream>>>(enc_q, enc_k, enc_v, Wq, Wk, Wv, qf, kf, vf);
    attn<<<408, 512, 0, stream>>>(qf, kf, vf, out, Op, Dp);
    combine<<<dim3(26, 4, 4), 256, 0, stream>>>(Op, Dp, out);
}

// Round 7
// 225.604 us; speedup vs baseline: 1.1762x; 1.1762x over previous
//
#include <hip/hip_runtime.h>

// Causal single-head attention, B=4 S=4096 Dm=256 Dqk=64, fp32 in/out.
// R7: e-split co-residency. R6 showed 2 blocks/CU thrashes L2 when co-resident
// blocks have disjoint kv windows (FETCH 12->100MB). Fix: pair blocks =
// (task, e-half): same task, same S^T (duplicated QK^T, +20% MFMA), same
// kf/qf reads, static vf halves -> XCD footprint ~3MB in L2. Grid 512=2x256,
// pair (bid,bid+256) shares an XCD. PV per wave: 1 e-tile x 2 q-subs (oa[2]).
// Also: batched vf loads (8 chunks issued before PV MFMAs), ws shrunk to
// 19.5MB (chunk0 of split tasks writes unnormalized fp32 direct to d_out; Op
// holds only chunks>=1: 28 slots/batch). R3 task map (nc=1/2/3), loop order
// S^T -> pack -> barrier -> prefetch -> PV (R5 rotation regressed).
// ws: qf 2MB + kf 2MB + vf 8MB + Op 7.34MB + Dp 98KB = 19.5MB.

#define BATCH 4
#define SEQ   4096
#define DM    256
#define DQK   64

typedef __bf16 bf16x8 __attribute__((ext_vector_type(8)));
typedef float  f32x16 __attribute__((ext_vector_type(16)));

__device__ __forceinline__ unsigned int rnd16(unsigned int u) {
    return u + 0x7fffu + ((u >> 16) & 1u);          // RNE to bf16 in high half
}
__device__ __forceinline__ unsigned short f2bf(float f) {
    return (unsigned short)(rnd16(__builtin_bit_cast(unsigned int, f)) >> 16);
}
__device__ __forceinline__ unsigned int pk2bf(float lo, float hi) {
    unsigned int a = rnd16(__builtin_bit_cast(unsigned int, lo));
    unsigned int b = rnd16(__builtin_bit_cast(unsigned int, hi));
    return (a >> 16) | (b & 0xffff0000u);           // elem0 low, elem1 high
}
__device__ __forceinline__ bf16x8 u4bf(uint4 u) { return __builtin_bit_cast(bf16x8, u); }

// Repack a 32x32x16 MFMA accumulator D[m][n] (C-layout: col(n)=lane&31,
// row(m)=(r&3)+8(r>>2)+4(lane>>5)) into two 1KB fragment chunks where the
// fragment k-dim = m and lane-dim = n, then store. (Verified R2/R3.)
__device__ __forceinline__ void repack_store(const f32x16& acc, int q2, int l,
                                             uint4* __restrict__ out, size_t tile_ofs_u4) {
    unsigned int d0[4], d1[4], p0[4], p1[4];
#pragma unroll
    for (int h = 0; h < 4; ++h) {
        d0[h] = pk2bf(acc[4*h + 0], acc[4*h + 1]);
        d1[h] = pk2bf(acc[4*h + 2], acc[4*h + 3]);
        p0[h] = __shfl_xor((int)d0[h], 32);
        p1[h] = __shfl_xor((int)d1[h], 32);
    }
#pragma unroll
    for (int kc = 0; kc < 2; ++kc) {
        int h = 2*kc + q2;
        uint4 v = (q2 == 0) ? make_uint4(d0[h], d1[h], p0[h], p1[h])
                            : make_uint4(p0[h], p1[h], d0[h], d1[h]);
        out[tile_ofs_u4 + (size_t)kc * 64 + l] = v;
    }
}

// R3 task map: nc=1 (T<12), 2 (12..23), 3 (24..31).
// Op slots (chunks cc>=1): T 12..23 -> 1 slot, 24..31 -> 2. 28/batch.
__device__ __forceinline__ int obase(int T) {
    return (T < 24) ? (T - 12) : 12 + (T - 24) * 2;
}
// Dp slots (all chunks of split tasks): 48/batch.
__device__ __forceinline__ int dbase(int T) {
    return (T < 24) ? (T - 12) * 2 : 24 + (T - 24) * 3;
}

// ---------------------------------------------------------------------------
// Fused projection. grid (64 s-tiles, 4 batch, 4): z=0 Q, z=1 K, z=2 V(ec 0,1),
// z=3 V(ec 2,3). Coalesced fp32 staging -> bf16 LDS -> 32x32x16 MFMA ->
// frag-packed ws.
// ---------------------------------------------------------------------------
__global__ __launch_bounds__(256) void proj(const float* __restrict__ Xq,
                                            const float* __restrict__ Xk,
                                            const float* __restrict__ Xv,
                                            const float* __restrict__ Wq,
                                            const float* __restrict__ Wk,
                                            const float* __restrict__ Wv,
                                            uint4* __restrict__ qf,
                                            uint4* __restrict__ kf,
                                            uint4* __restrict__ vf) {
    __shared__ unsigned short Xs[64][264];
    __shared__ unsigned short Ws[64][264];

    const int z = blockIdx.z;
    const int bx = blockIdx.x, b = blockIdx.y;
    const float* X = (z == 0) ? Xq : (z == 1) ? Xk : Xv;
    const float* W = (z == 0) ? Wq : (z == 1) ? Wk : Wv;
    const int s0 = bx * 64;
    const int tid = threadIdx.x, w = tid >> 6, l = tid & 63, ln = l & 31, q2 = l >> 5;

#pragma unroll
    for (int i = 0; i < 16; ++i) {
        int f = i * 256 + tid;
        int r = f >> 6, c4 = f & 63;
        float4 xv = *(const float4*)&X[((size_t)b * SEQ + s0 + r) * DM + c4 * 4];
        ushort4 h; h.x = f2bf(xv.x); h.y = f2bf(xv.y); h.z = f2bf(xv.z); h.w = f2bf(xv.w);
        *(ushort4*)&Xs[r][c4 * 4] = h;
    }

    if (z < 2) {
        // ---- Q/K: D[m=e (64)][n=s (64)] ----
#pragma unroll
        for (int i = 0; i < 16; ++i) {
            int f = i * 256 + tid;
            int r = f >> 6, c4 = f & 63;
            float4 wv = *(const float4*)&W[(size_t)r * DM + c4 * 4];
            ushort4 h; h.x = f2bf(wv.x); h.y = f2bf(wv.y); h.z = f2bf(wv.z); h.w = f2bf(wv.w);
            *(ushort4*)&Ws[r][c4 * 4] = h;
        }
        __syncthreads();
        const int msub = w >> 1, nsub = w & 1;
        f32x16 a0 = {}, a1 = {};
#pragma unroll
        for (int c = 0; c < 16; c += 2) {
            bf16x8 af0 = u4bf(*(const uint4*)&Ws[msub*32 + ln][c*16 + q2*8]);
            bf16x8 bf0 = u4bf(*(const uint4*)&Xs[nsub*32 + ln][c*16 + q2*8]);
            a0 = __builtin_amdgcn_mfma_f32_32x32x16_bf16(af0, bf0, a0, 0, 0, 0);
            bf16x8 af1 = u4bf(*(const uint4*)&Ws[msub*32 + ln][(c+1)*16 + q2*8]);
            bf16x8 bf1 = u4bf(*(const uint4*)&Xs[nsub*32 + ln][(c+1)*16 + q2*8]);
            a1 = __builtin_amdgcn_mfma_f32_32x32x16_bf16(af1, bf1, a1, 0, 0, 0);
        }
        f32x16 acc = a0 + a1;
        size_t base = (((size_t)(b*128 + bx*2 + nsub)) * 4 + 2*msub) * 64;
        repack_store(acc, q2, l, (z == 0) ? qf : kf, base);
    } else {
        // ---- V: D[m=s (64)][n=e], e-chunks (z-2)*2 .. +1 ----
        const int msub = w & 1, nsub = w >> 1;
        for (int ecl = 0; ecl < 2; ++ecl) {
            const int ec = (z - 2) * 2 + ecl;
            __syncthreads();
#pragma unroll
            for (int i = 0; i < 16; ++i) {
                int f = i * 256 + tid;
                int r = f >> 6, c4 = f & 63;
                float4 wv = *(const float4*)&W[(size_t)(ec*64 + r) * DM + c4 * 4];
                ushort4 h; h.x = f2bf(wv.x); h.y = f2bf(wv.y); h.z = f2bf(wv.z); h.w = f2bf(wv.w);
                *(ushort4*)&Ws[r][c4 * 4] = h;
            }
            __syncthreads();
            f32x16 a0 = {}, a1 = {};
#pragma unroll
            for (int c = 0; c < 16; c += 2) {
                bf16x8 af0 = u4bf(*(const uint4*)&Xs[msub*32 + ln][c*16 + q2*8]);
                bf16x8 bf0 = u4bf(*(const uint4*)&Ws[nsub*32 + ln][c*16 + q2*8]);
                a0 = __builtin_amdgcn_mfma_f32_32x32x16_bf16(af0, bf0, a0, 0, 0, 0);
                bf16x8 af1 = u4bf(*(const uint4*)&Xs[msub*32 + ln][(c+1)*16 + q2*8]);
                bf16x8 bf1 = u4bf(*(const uint4*)&Ws[nsub*32 + ln][(c+1)*16 + q2*8]);
                a1 = __builtin_amdgcn_mfma_f32_32x32x16_bf16(af1, bf1, a1, 0, 0, 0);
            }
            f32x16 acc = a0 + a1;
            int et = ec*2 + nsub;
            size_t base = (((size_t)(b*8 + et)) * 256 + (size_t)bx*4 + msub*2) * 64;
            repack_store(acc, q2, l, vf, base);
        }
    }
}

// ---------------------------------------------------------------------------
// Attention. Grid 512 x 512 thr (2 blocks/CU). bid = eh*256 + r:
// eh = e-half, r -> (slot = r&7 -> b,parity; u = r>>3; task = 2u+parity).
// Pair (bid, bid+256) = same task, e-halves 0/1 -> same XCD, same kf/qf
// reads, static vf halves. S^T duplicated across the pair; PV per wave =
// e-tile eh*4+(w&3), q-subs 2*(w>>2)..+1.
// ---------------------------------------------------------------------------
__global__ __launch_bounds__(512, 4) void attn(const uint4* __restrict__ qf,
                                               const uint4* __restrict__ kf,
                                               const uint4* __restrict__ vf,
                                               float* __restrict__ out,
                                               unsigned short* __restrict__ Op,
                                               float* __restrict__ Dp) {
    __shared__ uint4 Pb[2][4][8][64];        // 64KB, double-buffered P
    __shared__ float denp[8][2][64];
    __shared__ float dfin[128];

    const int bid = blockIdx.x;
    const int eh = bid >> 8, r_ = bid & 255;
    const int slot = r_ & 7, u = r_ >> 3;
    const int b = slot >> 1;
    const int task = u * 2 + (slot & 1);
    if (task >= 60) return;                  // 16 idle pad blocks per e-half
    int T, cc, nc;
    if (task < 12)      { T = task;                cc = 0;               nc = 1; }
    else if (task < 36) { int q = task - 12; T = 12 + (q >> 1); cc = q & 1;       nc = 2; }
    else                { int q = task - 36; T = 24 + q / 3;    cc = q - 3*(q/3); nc = 3; }
    const int n = T + 1;
    const int j0 = cc * n / nc, j1 = (cc + 1) * n / nc;

    const int tid = threadIdx.x, w = tid >> 6, l = tid & 63, ln = l & 31, q2 = l >> 5;
    const int ks = w & 3, qp = w >> 2;       // S^T: k-sub, q-pair
    const int etl = w & 3, qh = w >> 2;      // PV: e-tile-local, q-half
    const int et = eh * 4 + etl;             // global e-tile
    const float cfac = 0.18033688011112042f; // log2(e)/sqrt(64)

    bf16x8 qv[2][4];
#pragma unroll
    for (int g = 0; g < 2; ++g)
#pragma unroll
        for (int c = 0; c < 4; ++c)
            qv[g][c] = u4bf(qf[(((size_t)b*128 + T*4 + qp*2 + g) * 4 + c) * 64 + l]);

    f32x16 oa[2] = {};                       // O[q-sub qh*2+j][e-tile et]
    float den[2] = {0.f, 0.f};

    uint4 kaf[4];
#pragma unroll
    for (int c = 0; c < 4; ++c)
        kaf[c] = kf[(((size_t)b*128 + j0*4 + ks) * 4 + c) * 64 + l];

    for (int jt = j0; jt < j1; ++jt) {
        const int buf = jt & 1;
        const bool diag = (jt == T);
        // ---- S^T (identical in both e-halves) ----
        f32x16 s0 = {}, s1 = {};
#pragma unroll
        for (int c = 0; c < 4; ++c) {
            bf16x8 ka = u4bf(kaf[c]);
            s0 = __builtin_amdgcn_mfma_f32_32x32x16_bf16(ka, qv[0][c], s0, 0, 0, 0);
            s1 = __builtin_amdgcn_mfma_f32_32x32x16_bf16(ka, qv[1][c], s1, 0, 0, 0);
        }
        // ---- exp + mask + den + pack P -> LDS ----
#pragma unroll
        for (int g = 0; g < 2; ++g) {
            const f32x16 s = g ? s1 : s0;
            const int qsub = qp*2 + g;
            float pv[16], pd = 0.f;
#pragma unroll
            for (int r = 0; r < 16; ++r) {
                float e = __builtin_exp2f(s[r] * cfac);
                if (diag) {
                    int klocal = 4*q2 + (r & 3) + 8*(r >> 2);
                    if (ks*32 + klocal > qsub*32 + ln) e = 0.f;
                }
                pv[r] = e; pd += e;
            }
            den[g] += pd;
#pragma unroll
            for (int quad = 0; quad < 4; ++quad) {
                unsigned int lo = pk2bf(pv[4*quad + 0], pv[4*quad + 1]);
                unsigned int hi = pk2bf(pv[4*quad + 2], pv[4*quad + 3]);
                int kcg = ks*2 + (quad >> 1);
                int h   = quad & 1;
                char* dst = (char*)&Pb[buf][qsub][kcg][h*32 + ln] + q2*8;
                *(uint2*)dst = make_uint2(lo, hi);
            }
        }
        __syncthreads();
        // prefetch next K-frags + batch all 8 V-chunk loads (parallel in flight)
        if (jt + 1 < j1) {
#pragma unroll
            for (int c = 0; c < 4; ++c)
                kaf[c] = kf[(((size_t)b*128 + (jt+1)*4 + ks) * 4 + c) * 64 + l];
        }
        uint4 vbs[8];
#pragma unroll
        for (int kc = 0; kc < 8; ++kc)
            vbs[kc] = vf[(((size_t)b*8 + et) * 256 + (size_t)jt*8 + kc) * 64 + l];
        // ---- PV: O[q-sub][e-tile et] += P * V ----
#pragma unroll
        for (int kc = 0; kc < 8; ++kc) {
            bf16x8 vb = u4bf(vbs[kc]);
            bf16x8 pa0 = u4bf(Pb[buf][qh*2 + 0][kc][l]);
            oa[0] = __builtin_amdgcn_mfma_f32_32x32x16_bf16(pa0, vb, oa[0], 0, 0, 0);
            bf16x8 pa1 = u4bf(Pb[buf][qh*2 + 1][kc][l]);
            oa[1] = __builtin_amdgcn_mfma_f32_32x32x16_bf16(pa1, vb, oa[1], 0, 0, 0);
        }
    }

    // ---- den reduction across waves/halves (identical in both e-halves) ----
    denp[w][0][l] = den[0];
    denp[w][1][l] = den[1];
    __syncthreads();
    if (tid < 128) {
        int qsub = tid >> 5, qln = tid & 31;
        int g = qsub & 1, wp = qsub >> 1;
        float sden = 0.f;
#pragma unroll
        for (int k4 = 0; k4 < 4; ++k4)
#pragma unroll
            for (int hh = 0; hh < 2; ++hh)
                sden += denp[wp*4 + k4][g][hh*32 + qln];
        dfin[tid] = (nc == 1) ? 1.0f / sden : sden;
    }
    __syncthreads();

    const int col = et*32 + ln;
    if (nc == 1) {
#pragma unroll
        for (int j = 0; j < 2; ++j)
#pragma unroll
            for (int r = 0; r < 16; ++r) {
                int qrow = (qh*2 + j)*32 + (r & 3) + 8*(r >> 2) + 4*q2;
                out[((size_t)b*SEQ + T*128 + qrow) * DM + col] = oa[j][r] * dfin[qrow];
            }
    } else if (cc == 0) {
        // chunk 0: unnormalized fp32 straight into out (combine divides later)
#pragma unroll
        for (int j = 0; j < 2; ++j)
#pragma unroll
            for (int r = 0; r < 16; ++r) {
                int qrow = (qh*2 + j)*32 + (r & 3) + 8*(r >> 2) + 4*q2;
                out[((size_t)b*SEQ + T*128 + qrow) * DM + col] = oa[j][r];
            }
        if (eh == 0 && tid < 128) Dp[((size_t)b*48 + dbase(T)) * 128 + tid] = dfin[tid];
    } else {
        size_t pidx = (size_t)b*28 + obase(T) + (cc - 1);
#pragma unroll
        for (int j = 0; j < 2; ++j)
#pragma unroll
            for (int r = 0; r < 16; ++r) {
                int qrow = (qh*2 + j)*32 + (r & 3) + 8*(r >> 2) + 4*q2;
                Op[(pidx*128 + qrow) * DM + col] = f2bf(oa[j][r]);
            }
        if (eh == 0 && tid < 128) Dp[((size_t)b*48 + dbase(T) + cc) * 128 + tid] = dfin[tid];
    }
}

// ---------------------------------------------------------------------------
// Combine partials for T in [12,32). grid (20, 4, 4 q-quarters) x 256 thr.
// out holds chunk-0's unnormalized fp32; add bf16 chunks >=1, divide by den.
// ---------------------------------------------------------------------------
__global__ __launch_bounds__(256) void combine(const unsigned short* __restrict__ Op,
                                               const float* __restrict__ Dp,
                                               float* __restrict__ out) {
    const int T = 12 + blockIdx.x, b = blockIdx.y, qq = blockIdx.z;
    const int nc = (T < 24) ? 2 : 3;
    const int t = threadIdx.x;
    const size_t db = (size_t)b*48 + dbase(T);
    const size_t pb = (size_t)b*28 + obase(T);
#pragma unroll 4
    for (int r = 0; r < 32; ++r) {
        int q = qq*32 + r;
        size_t oofs = ((size_t)b*SEQ + T*128 + q) * DM + t;
        float sum = out[oofs];
        float dsum = 0.f;
        for (int c = 0; c < nc; ++c) dsum += Dp[(db + c)*128 + q];
        for (int c = 1; c < nc; ++c) {
            unsigned int uv = Op[((pb + c - 1)*128 + q) * DM + t];
            sum += __builtin_bit_cast(float, uv << 16);
        }
        out[oofs] = sum / dsum;
    }
}

// ---------------------------------------------------------------------------
extern "C" void kernel_launch(void* const* d_in, const int* in_sizes, int n_in,
                              void* d_out, int out_size, void* d_ws, size_t ws_size,
                              hipStream_t stream) {
    const float* enc_q = (const float*)d_in[0];
    const float* enc_k = (const float*)d_in[1];
    const float* enc_v = (const float*)d_in[2];
    // d_in[3] = mask (deterministic causal triu) — not needed
    const float* Wq = (const float*)d_in[4];
    const float* Wk = (const float*)d_in[5];
    const float* Wv = (const float*)d_in[6];
    float* out = (float*)d_out;

    uint4* qf = (uint4*)d_ws;                              // 2MB
    uint4* kf = qf + 131072;                               // 2MB
    uint4* vf = kf + 131072;                               // 8MB
    unsigned short* Op = (unsigned short*)(vf + 524288);   // [4][28][128][256] bf16, 7.34MB
    float* Dp = (float*)(Op + (size_t)4*28*128*256);       // [4][48][128] f32, 98KB

    proj<<<dim3(64, 4, 4), 256, 0, stream>>>(enc_q, enc_k, enc_v, Wq, Wk, Wv, qf, kf, vf);
    attn<<<512, 512, 0, stream>>>(qf, kf, vf, out, Op, Dp);
    combine<<<dim3(20, 4, 4), 256, 0, stream>>>(Op, Dp, out);
}

// Round 8
// 206.691 us; speedup vs baseline: 1.2838x; 1.0915x over previous
//
#include <hip/hip_runtime.h>

// Causal single-head attention, B=4 S=4096 Dm=256 Dqk=64, fp32 in/out.
// R8: R3's proven 240-block/1-per-CU attention (no softmax duplication, L2
// footprint 3MB/XCD) + the latency fix R7 accidentally validated: batch all
// 8 vf chunk loads at the TOP of each iteration (before S^T/exp/pack), so
// their ~200cyc L2 latency is covered by independent work instead of
// serializing load->use inside the PV loop (R3 lost ~1.8K cyc/iter there).
// kaf prefetched across the barrier as before. Lean ws from R7 (19.5MB):
// split-task chunk0 writes unnormalized fp32 direct to d_out, Op holds only
// chunks>=1 (28 slots/batch), combine divides.
// ws: qf 2MB + kf 2MB + vf 8MB + Op 7.34MB + Dp 98KB = 19.5MB.

#define BATCH 4
#define SEQ   4096
#define DM    256
#define DQK   64

typedef __bf16 bf16x8 __attribute__((ext_vector_type(8)));
typedef float  f32x16 __attribute__((ext_vector_type(16)));

__device__ __forceinline__ unsigned int rnd16(unsigned int u) {
    return u + 0x7fffu + ((u >> 16) & 1u);          // RNE to bf16 in high half
}
__device__ __forceinline__ unsigned short f2bf(float f) {
    return (unsigned short)(rnd16(__builtin_bit_cast(unsigned int, f)) >> 16);
}
__device__ __forceinline__ unsigned int pk2bf(float lo, float hi) {
    unsigned int a = rnd16(__builtin_bit_cast(unsigned int, lo));
    unsigned int b = rnd16(__builtin_bit_cast(unsigned int, hi));
    return (a >> 16) | (b & 0xffff0000u);           // elem0 low, elem1 high
}
__device__ __forceinline__ bf16x8 u4bf(uint4 u) { return __builtin_bit_cast(bf16x8, u); }

// Repack a 32x32x16 MFMA accumulator D[m][n] (C-layout: col(n)=lane&31,
// row(m)=(r&3)+8(r>>2)+4(lane>>5)) into two 1KB fragment chunks where the
// fragment k-dim = m and lane-dim = n, then store. (Verified R2/R3.)
__device__ __forceinline__ void repack_store(const f32x16& acc, int q2, int l,
                                             uint4* __restrict__ out, size_t tile_ofs_u4) {
    unsigned int d0[4], d1[4], p0[4], p1[4];
#pragma unroll
    for (int h = 0; h < 4; ++h) {
        d0[h] = pk2bf(acc[4*h + 0], acc[4*h + 1]);
        d1[h] = pk2bf(acc[4*h + 2], acc[4*h + 3]);
        p0[h] = __shfl_xor((int)d0[h], 32);
        p1[h] = __shfl_xor((int)d1[h], 32);
    }
#pragma unroll
    for (int kc = 0; kc < 2; ++kc) {
        int h = 2*kc + q2;
        uint4 v = (q2 == 0) ? make_uint4(d0[h], d1[h], p0[h], p1[h])
                            : make_uint4(p0[h], p1[h], d0[h], d1[h]);
        out[tile_ofs_u4 + (size_t)kc * 64 + l] = v;
    }
}

// R3 task map: nc=1 (T<12), 2 (12..23), 3 (24..31).
// Op slots (chunks cc>=1): T 12..23 -> 1 slot, 24..31 -> 2. 28/batch.
__device__ __forceinline__ int obase(int T) {
    return (T < 24) ? (T - 12) : 12 + (T - 24) * 2;
}
// Dp slots (all chunks of split tasks): 48/batch.
__device__ __forceinline__ int dbase(int T) {
    return (T < 24) ? (T - 12) * 2 : 24 + (T - 24) * 3;
}

// ---------------------------------------------------------------------------
// Fused projection. grid (64 s-tiles, 4 batch, 4): z=0 Q, z=1 K, z=2 V(ec 0,1),
// z=3 V(ec 2,3). Coalesced fp32 staging -> bf16 LDS -> 32x32x16 MFMA ->
// frag-packed ws.
// ---------------------------------------------------------------------------
__global__ __launch_bounds__(256) void proj(const float* __restrict__ Xq,
                                            const float* __restrict__ Xk,
                                            const float* __restrict__ Xv,
                                            const float* __restrict__ Wq,
                                            const float* __restrict__ Wk,
                                            const float* __restrict__ Wv,
                                            uint4* __restrict__ qf,
                                            uint4* __restrict__ kf,
                                            uint4* __restrict__ vf) {
    __shared__ unsigned short Xs[64][264];
    __shared__ unsigned short Ws[64][264];

    const int z = blockIdx.z;
    const int bx = blockIdx.x, b = blockIdx.y;
    const float* X = (z == 0) ? Xq : (z == 1) ? Xk : Xv;
    const float* W = (z == 0) ? Wq : (z == 1) ? Wk : Wv;
    const int s0 = bx * 64;
    const int tid = threadIdx.x, w = tid >> 6, l = tid & 63, ln = l & 31, q2 = l >> 5;

#pragma unroll
    for (int i = 0; i < 16; ++i) {
        int f = i * 256 + tid;
        int r = f >> 6, c4 = f & 63;
        float4 xv = *(const float4*)&X[((size_t)b * SEQ + s0 + r) * DM + c4 * 4];
        ushort4 h; h.x = f2bf(xv.x); h.y = f2bf(xv.y); h.z = f2bf(xv.z); h.w = f2bf(xv.w);
        *(ushort4*)&Xs[r][c4 * 4] = h;
    }

    if (z < 2) {
        // ---- Q/K: D[m=e (64)][n=s (64)] ----
#pragma unroll
        for (int i = 0; i < 16; ++i) {
            int f = i * 256 + tid;
            int r = f >> 6, c4 = f & 63;
            float4 wv = *(const float4*)&W[(size_t)r * DM + c4 * 4];
            ushort4 h; h.x = f2bf(wv.x); h.y = f2bf(wv.y); h.z = f2bf(wv.z); h.w = f2bf(wv.w);
            *(ushort4*)&Ws[r][c4 * 4] = h;
        }
        __syncthreads();
        const int msub = w >> 1, nsub = w & 1;
        f32x16 a0 = {}, a1 = {};
#pragma unroll
        for (int c = 0; c < 16; c += 2) {
            bf16x8 af0 = u4bf(*(const uint4*)&Ws[msub*32 + ln][c*16 + q2*8]);
            bf16x8 bf0 = u4bf(*(const uint4*)&Xs[nsub*32 + ln][c*16 + q2*8]);
            a0 = __builtin_amdgcn_mfma_f32_32x32x16_bf16(af0, bf0, a0, 0, 0, 0);
            bf16x8 af1 = u4bf(*(const uint4*)&Ws[msub*32 + ln][(c+1)*16 + q2*8]);
            bf16x8 bf1 = u4bf(*(const uint4*)&Xs[nsub*32 + ln][(c+1)*16 + q2*8]);
            a1 = __builtin_amdgcn_mfma_f32_32x32x16_bf16(af1, bf1, a1, 0, 0, 0);
        }
        f32x16 acc = a0 + a1;
        size_t base = (((size_t)(b*128 + bx*2 + nsub)) * 4 + 2*msub) * 64;
        repack_store(acc, q2, l, (z == 0) ? qf : kf, base);
    } else {
        // ---- V: D[m=s (64)][n=e], e-chunks (z-2)*2 .. +1 ----
        const int msub = w & 1, nsub = w >> 1;
        for (int ecl = 0; ecl < 2; ++ecl) {
            const int ec = (z - 2) * 2 + ecl;
            __syncthreads();
#pragma unroll
            for (int i = 0; i < 16; ++i) {
                int f = i * 256 + tid;
                int r = f >> 6, c4 = f & 63;
                float4 wv = *(const float4*)&W[(size_t)(ec*64 + r) * DM + c4 * 4];
                ushort4 h; h.x = f2bf(wv.x); h.y = f2bf(wv.y); h.z = f2bf(wv.z); h.w = f2bf(wv.w);
                *(ushort4*)&Ws[r][c4 * 4] = h;
            }
            __syncthreads();
            f32x16 a0 = {}, a1 = {};
#pragma unroll
            for (int c = 0; c < 16; c += 2) {
                bf16x8 af0 = u4bf(*(const uint4*)&Xs[msub*32 + ln][c*16 + q2*8]);
                bf16x8 bf0 = u4bf(*(const uint4*)&Ws[nsub*32 + ln][c*16 + q2*8]);
                a0 = __builtin_amdgcn_mfma_f32_32x32x16_bf16(af0, bf0, a0, 0, 0, 0);
                bf16x8 af1 = u4bf(*(const uint4*)&Xs[msub*32 + ln][(c+1)*16 + q2*8]);
                bf16x8 bf1 = u4bf(*(const uint4*)&Ws[nsub*32 + ln][(c+1)*16 + q2*8]);
                a1 = __builtin_amdgcn_mfma_f32_32x32x16_bf16(af1, bf1, a1, 0, 0, 0);
            }
            f32x16 acc = a0 + a1;
            int et = ec*2 + nsub;
            size_t base = (((size_t)(b*8 + et)) * 256 + (size_t)bx*4 + msub*2) * 64;
            repack_store(acc, q2, l, vf, base);
        }
    }
}

// ---------------------------------------------------------------------------
// Attention. 240 blocks x 512 thr, 1 block/CU. Task = (b, T, chunk cc of nc).
// slot = bid&7 -> b = slot>>1, parity = slot&1 (XCD batch-pinning, L2-proven).
// Wave w: S^T tile (k-sub w&3, q-pair w>>2), PV e-tile w, 4 q-subs.
// Iter: batch-load vbs[8] (latency hidden by S^T/exp/pack) -> S^T -> exp/pack
// -> barrier -> kaf prefetch -> PV from vbs.
// ---------------------------------------------------------------------------
__global__ __launch_bounds__(512, 2) void attn(const uint4* __restrict__ qf,
                                               const uint4* __restrict__ kf,
                                               const uint4* __restrict__ vf,
                                               float* __restrict__ out,
                                               unsigned short* __restrict__ Op,
                                               float* __restrict__ Dp) {
    __shared__ uint4 Pb[2][4][8][64];        // 64KB, double-buffered P
    __shared__ float denp[8][2][64];
    __shared__ float dfin[128];

    const int bid = blockIdx.x;
    const int slot = bid & 7, u = bid >> 3;
    const int b = slot >> 1;
    const int task = u * 2 + (slot & 1);     // [0,60)
    int T, cc, nc;
    if (task < 12)      { T = task;                cc = 0;               nc = 1; }
    else if (task < 36) { int q = task - 12; T = 12 + (q >> 1); cc = q & 1;       nc = 2; }
    else                { int q = task - 36; T = 24 + q / 3;    cc = q - 3*(q/3); nc = 3; }
    const int n = T + 1;
    const int j0 = cc * n / nc, j1 = (cc + 1) * n / nc;

    const int tid = threadIdx.x, w = tid >> 6, l = tid & 63, ln = l & 31, q2 = l >> 5;
    const int ks = w & 3, qp = w >> 2;
    const float cfac = 0.18033688011112042f; // log2(e)/sqrt(64)

    bf16x8 qv[2][4];
#pragma unroll
    for (int g = 0; g < 2; ++g)
#pragma unroll
        for (int c = 0; c < 4; ++c)
            qv[g][c] = u4bf(qf[(((size_t)b*128 + T*4 + qp*2 + g) * 4 + c) * 64 + l]);

    f32x16 oa[4] = {};
    float den[2] = {0.f, 0.f};

    uint4 kaf[4];
#pragma unroll
    for (int c = 0; c < 4; ++c)
        kaf[c] = kf[(((size_t)b*128 + j0*4 + ks) * 4 + c) * 64 + l];

    for (int jt = j0; jt < j1; ++jt) {
        const int buf = jt & 1;
        const bool diag = (jt == T);

        // ---- batch V-chunk loads for THIS iter (latency covered below) ----
        uint4 vbs[8];
#pragma unroll
        for (int kc = 0; kc < 8; ++kc)
            vbs[kc] = vf[(((size_t)b*8 + w) * 256 + (size_t)jt*8 + kc) * 64 + l];

        // ---- S^T ----
        f32x16 s0 = {}, s1 = {};
#pragma unroll
        for (int c = 0; c < 4; ++c) {
            bf16x8 ka = u4bf(kaf[c]);
            s0 = __builtin_amdgcn_mfma_f32_32x32x16_bf16(ka, qv[0][c], s0, 0, 0, 0);
            s1 = __builtin_amdgcn_mfma_f32_32x32x16_bf16(ka, qv[1][c], s1, 0, 0, 0);
        }
        // ---- exp + mask + den + pack P -> LDS ----
#pragma unroll
        for (int g = 0; g < 2; ++g) {
            const f32x16 s = g ? s1 : s0;
            const int qsub = qp*2 + g;
            float pv[16], pd = 0.f;
#pragma unroll
            for (int r = 0; r < 16; ++r) {
                float e = __builtin_exp2f(s[r] * cfac);
                if (diag) {
                    int klocal = 4*q2 + (r & 3) + 8*(r >> 2);
                    if (ks*32 + klocal > qsub*32 + ln) e = 0.f;
                }
                pv[r] = e; pd += e;
            }
            den[g] += pd;
#pragma unroll
            for (int quad = 0; quad < 4; ++quad) {
                unsigned int lo = pk2bf(pv[4*quad + 0], pv[4*quad + 1]);
                unsigned int hi = pk2bf(pv[4*quad + 2], pv[4*quad + 3]);
                int kcg = ks*2 + (quad >> 1);
                int h   = quad & 1;
                char* dst = (char*)&Pb[buf][qsub][kcg][h*32 + ln] + q2*8;
                *(uint2*)dst = make_uint2(lo, hi);
            }
        }
        __syncthreads();
        // ---- prefetch next K-frags (covered by PV) ----
        if (jt + 1 < j1) {
#pragma unroll
            for (int c = 0; c < 4; ++c)
                kaf[c] = kf[(((size_t)b*128 + (jt+1)*4 + ks) * 4 + c) * 64 + l];
        }
        // ---- PV: O[q][e-tile w] += P * V (V already in regs) ----
#pragma unroll
        for (int kc = 0; kc < 8; ++kc) {
            bf16x8 vb = u4bf(vbs[kc]);
#pragma unroll
            for (int qs = 0; qs < 4; ++qs) {
                bf16x8 pa = u4bf(Pb[buf][qs][kc][l]);
                oa[qs] = __builtin_amdgcn_mfma_f32_32x32x16_bf16(pa, vb, oa[qs], 0, 0, 0);
            }
        }
    }

    // ---- den reduction across waves/halves ----
    denp[w][0][l] = den[0];
    denp[w][1][l] = den[1];
    __syncthreads();
    if (tid < 128) {
        int qsub = tid >> 5, qln = tid & 31;
        int g = qsub & 1, wp = qsub >> 1;
        float sden = 0.f;
#pragma unroll
        for (int k4 = 0; k4 < 4; ++k4)
#pragma unroll
            for (int hh = 0; hh < 2; ++hh)
                sden += denp[wp*4 + k4][g][hh*32 + qln];
        dfin[tid] = (nc == 1) ? 1.0f / sden : sden;
    }
    __syncthreads();

    if (nc == 1) {
#pragma unroll
        for (int qs = 0; qs < 4; ++qs)
#pragma unroll
            for (int r = 0; r < 16; ++r) {
                int qrow = qs*32 + (r & 3) + 8*(r >> 2) + 4*q2;
                out[((size_t)b*SEQ + T*128 + qrow) * DM + w*32 + ln] = oa[qs][r] * dfin[qrow];
            }
    } else if (cc == 0) {
        // chunk 0: unnormalized fp32 straight into out (combine divides later)
#pragma unroll
        for (int qs = 0; qs < 4; ++qs)
#pragma unroll
            for (int r = 0; r < 16; ++r) {
                int qrow = qs*32 + (r & 3) + 8*(r >> 2) + 4*q2;
                out[((size_t)b*SEQ + T*128 + qrow) * DM + w*32 + ln] = oa[qs][r];
            }
        if (tid < 128) Dp[((size_t)b*48 + dbase(T)) * 128 + tid] = dfin[tid];
    } else {
        size_t pidx = (size_t)b*28 + obase(T) + (cc - 1);
#pragma unroll
        for (int qs = 0; qs < 4; ++qs)
#pragma unroll
            for (int r = 0; r < 16; ++r) {
                int qrow = qs*32 + (r & 3) + 8*(r >> 2) + 4*q2;
                Op[(pidx*128 + qrow) * DM + w*32 + ln] = f2bf(oa[qs][r]);
            }
        if (tid < 128) Dp[((size_t)b*48 + dbase(T) + cc) * 128 + tid] = dfin[tid];
    }
}

// ---------------------------------------------------------------------------
// Combine partials for T in [12,32). grid (20, 4, 4 q-quarters) x 256 thr.
// out holds chunk-0's unnormalized fp32; add bf16 chunks >=1, divide by den.
// ---------------------------------------------------------------------------
__global__ __launch_bounds__(256) void combine(const unsigned short* __restrict__ Op,
                                               const float* __restrict__ Dp,
                                               float* __restrict__ out) {
    const int T = 12 + blockIdx.x, b = blockIdx.y, qq = blockIdx.z;
    const int nc = (T < 24) ? 2 : 3;
    const int t = threadIdx.x;
    const size_t db = (size_t)b*48 + dbase(T);
    const size_t pb = (size_t)b*28 + obase(T);
#pragma unroll 4
    for (int r = 0; r < 32; ++r) {
        int q = qq*32 + r;
        size_t oofs = ((size_t)b*SEQ + T*128 + q) * DM + t;
        float sum = out[oofs];
        float dsum = 0.f;
        for (int c = 0; c < nc; ++c) dsum += Dp[(db + c)*128 + q];
        for (int c = 1; c < nc; ++c) {
            unsigned int uv = Op[((pb + c - 1)*128 + q) * DM + t];
            sum += __builtin_bit_cast(float, uv << 16);
        }
        out[oofs] = sum / dsum;
    }
}

// ---------------------------------------------------------------------------
extern "C" void kernel_launch(void* const* d_in, const int* in_sizes, int n_in,
                              void* d_out, int out_size, void* d_ws, size_t ws_size,
                              hipStream_t stream) {
    const float* enc_q = (const float*)d_in[0];
    const float* enc_k = (const float*)d_in[1];
    const float* enc_v = (const float*)d_in[2];
    // d_in[3] = mask (deterministic causal triu) — not needed
    const float* Wq = (const float*)d_in[4];
    const float* Wk = (const float*)d_in[5];
    const float* Wv = (const float*)d_in[6];
    float* out = (float*)d_out;

    uint4* qf = (uint4*)d_ws;                              // 2MB
    uint4* kf = qf + 131072;                               // 2MB
    uint4* vf = kf + 131072;                               // 8MB
    unsigned short* Op = (unsigned short*)(vf + 524288);   // [4][28][128][256] bf16, 7.34MB
    float* Dp = (float*)(Op + (size_t)4*28*128*256);       // [4][48][128] f32, 98KB

    proj<<<dim3(64, 4, 4), 256, 0, stream>>>(enc_q, enc_k, enc_v, Wq, Wk, Wv, qf, kf, vf);
    attn<<<240, 512, 0, stream>>>(qf, kf, vf, out, Op, Dp);
    combine<<<dim3(20, 4, 4), 256, 0, stream>>>(Op, Dp, out);
}